// Round 3
// baseline (153.713 us; speedup 1.0000x reference)
//
#include <hip/hip_runtime.h>

#define NLOC 384

// ws layout: ab[384*64] f32 at byte 0 (96 KB); T[384*32*64] f32 at byte 98304 (3 MB).
// T[j][x][p] = sum_y b[j][y] * W_out[p][x*32+y]

// Fused: ab rows + T slices for 8 j's per block. Grid = 48.
__global__ __launch_bounds__(256) void k_prep(const float* __restrict__ m,
                                              const float* __restrict__ W_in,
                                              const float* __restrict__ b_in,
                                              const float* __restrict__ op_mask,
                                              const float* __restrict__ W_out,
                                              float* __restrict__ ab,
                                              float* __restrict__ T) {
    const int t  = threadIdx.x;
    const int h  = t & 63;
    const int rr = __builtin_amdgcn_readfirstlane(t >> 6);  // 0..3
    const int jb = blockIdx.x * 8;
    __shared__ float bsh[8][32];

    const float mask = op_mask[0];
    const float bi   = b_in[h];

    // Step 1: ab rows jb..jb+7. Thread (rr,h) does rows {jb+rr, jb+4+rr}.
#pragma unroll
    for (int rg = 0; rg < 2; ++rg) {
        const int n = jb + rg * 4 + rr;
        const float* mrow = m + n * 128;          // wave-uniform -> s_load
        const float* wrow = W_in + h * 128;
        float acc = 0.f;
#pragma unroll
        for (int q = 0; q < 32; ++q) {
            const float4 wv = *reinterpret_cast<const float4*>(wrow + q * 4);
            const float4 mv = *reinterpret_cast<const float4*>(mrow + q * 4);
            acc += wv.x * mv.x + wv.y * mv.y + wv.z * mv.z + wv.w * mv.w;
        }
        const float val = (acc + bi) * mask;
        ab[n * 64 + h] = val;
        if (h >= 32) bsh[rg * 4 + rr][h - 32] = val;   // b-half to LDS
    }
    __syncthreads();

    // Step 2: T[j][x][p] for the 8 j's. p = h, x = rr*8 + xs.
    const int p = h;
#pragma unroll
    for (int xs = 0; xs < 8; ++xs) {
        const int x = rr * 8 + xs;
        float4 w[8];
#pragma unroll
        for (int yq = 0; yq < 8; ++yq)
            w[yq] = *reinterpret_cast<const float4*>(W_out + p * 1024 + x * 32 + yq * 4);
#pragma unroll
        for (int jj = 0; jj < 8; ++jj) {
            float acc = 0.f;
#pragma unroll
            for (int yq = 0; yq < 8; ++yq) {
                const float4 b4 = *reinterpret_cast<const float4*>(&bsh[jj][yq * 4]); // LDS broadcast
                acc += b4.x * w[yq].x + b4.y * w[yq].y + b4.z * w[yq].z + b4.w * w[yq].w;
            }
            T[(jb + jj) * 2048 + x * 64 + p] = acc;   // lanes p consecutive
        }
    }
}

// out[i][j][p] = (sum_x a[i][x] * T[j][x][p] + b_out[p]) * op_norm
// Block = 16i x 16j tile. Wave w owns j-quad jbase = jt*16 + w*4.
// Lane: jq = lane>>4 (j within quad), p4 = (lane&15)*4.
// Store: one dwordx4 per (wave,i) = 1 KB contiguous across 64 lanes.
__global__ __launch_bounds__(256) void k_main2(const float* __restrict__ ab,
                                               const float* __restrict__ T,
                                               const float* __restrict__ b_out,
                                               const float* __restrict__ op_norm,
                                               float* __restrict__ out) {
    const int t    = threadIdx.x;
    const int lane = t & 63;
    const int wv   = __builtin_amdgcn_readfirstlane(t >> 6);  // 0..3
    const int bid  = blockIdx.x;
    const int jt   = bid % 24;
    const int it   = bid / 24;
    const int jq   = lane >> 4;
    const int p4   = (lane & 15) * 4;
    const int j    = jt * 16 + wv * 4 + jq;
    const int i0   = it * 16;

    const float4 bo  = *reinterpret_cast<const float4*>(b_out + p4);
    const float norm = op_norm[0];

    float4 acc[16];
#pragma unroll
    for (int i = 0; i < 16; ++i) acc[i] = bo;

    const float* Tj   = T + j * 2048 + p4;
    const float* arow = ab + i0 * 64;           // wave-uniform -> s_load

#pragma unroll 4
    for (int x = 0; x < 32; ++x) {
        const float4 t4 = *reinterpret_cast<const float4*>(Tj + x * 64);
#pragma unroll
        for (int i = 0; i < 16; ++i) {
            const float a = arow[i * 64 + x];   // scalar (SGPR) operand
            acc[i].x += a * t4.x;
            acc[i].y += a * t4.y;
            acc[i].z += a * t4.z;
            acc[i].w += a * t4.w;
        }
    }

#pragma unroll
    for (int i = 0; i < 16; ++i) {
        float4 r;
        r.x = acc[i].x * norm; r.y = acc[i].y * norm;
        r.z = acc[i].z * norm; r.w = acc[i].w * norm;
        *reinterpret_cast<float4*>(out + ((i0 + i) * NLOC + j) * 64 + p4) = r;
    }
}

extern "C" void kernel_launch(void* const* d_in, const int* in_sizes, int n_in,
                              void* d_out, int out_size, void* d_ws, size_t ws_size,
                              hipStream_t stream) {
    const float* m       = (const float*)d_in[0];
    // d_in[1] = nlist (unused by the reference computation)
    const float* op_mask = (const float*)d_in[2];
    const float* op_norm = (const float*)d_in[3];
    const float* W_in    = (const float*)d_in[4];
    const float* b_in    = (const float*)d_in[5];
    const float* W_out   = (const float*)d_in[6];
    const float* b_out   = (const float*)d_in[7];
    float* out = (float*)d_out;

    float* ab = (float*)d_ws;                      // 384*64 f32
    float* T  = (float*)((char*)d_ws + 98304);     // 384*32*64 f32

    k_prep <<<48,  256, 0, stream>>>(m, W_in, b_in, op_mask, W_out, ab, T);
    k_main2<<<576, 256, 0, stream>>>(ab, T, b_out, op_norm, out);
}

// Round 5
// 109.927 us; speedup vs baseline: 1.3983x; 1.3983x over previous
//
#include <hip/hip_runtime.h>

#define NLOC 384

// ws layout: ab[384*64] f32 at byte 0 (96 KB); T[384*32*64] f32 at byte 98304 (3 MB).
// T[j][x*64+p] = sum_y b[j][y] * W_out[p][x*32+y],  b[j][y] = ab[j*64+32+y]

// ab[n][h] = (sum_d m[n,d] * W_in[h,d] + b_in[h]) * op_mask    grid=96
__global__ __launch_bounds__(256) void k_ab(const float* __restrict__ m,
                                            const float* __restrict__ W_in,
                                            const float* __restrict__ b_in,
                                            const float* __restrict__ op_mask,
                                            float* __restrict__ ab) {
    const int t  = threadIdx.x;
    const int h  = t & 63;
    const int ng = __builtin_amdgcn_readfirstlane(t >> 6);
    const int n  = blockIdx.x * 4 + ng;
    const float* mrow = m + n * 128;         // wave-uniform -> s_load
    const float* wrow = W_in + h * 128;      // 512 B contiguous per thread
    float acc = 0.f;
#pragma unroll
    for (int dq = 0; dq < 32; ++dq) {
        const float4 w  = *reinterpret_cast<const float4*>(wrow + dq * 4);
        const float4 mv = *reinterpret_cast<const float4*>(mrow + dq * 4);
        acc += w.x * mv.x + w.y * mv.y + w.z * mv.z + w.w * mv.w;
    }
    ab[n * 64 + h] = (acc + b_in[h]) * op_mask[0];
}

// T: grid=768, block=256. Block handles j=bid>>1, xp half = bid&1.
// Thread t owns xp0 = half*1024 + 4t .. +3  (same x, 4 consecutive p).
// Per-thread W_out reads are 4 x 128 B contiguous; T store is one dwordx4.
__global__ __launch_bounds__(256) void k_T(const float* __restrict__ ab,
                                           const float* __restrict__ W_out,
                                           float* __restrict__ T) {
    const int t    = threadIdx.x;
    const int j    = blockIdx.x >> 1;
    const int half = blockIdx.x & 1;
    const int xp0  = half * 1024 + t * 4;
    const int x    = xp0 >> 6;
    const int p0   = xp0 & 63;

    const float* brow = ab + j * 64 + 32;    // wave-uniform -> s_load broadcast
    float4 acc;
    float* accp = reinterpret_cast<float*>(&acc);
#pragma unroll 2
    for (int pp = 0; pp < 4; ++pp) {
        const float* wb = W_out + (p0 + pp) * 1024 + x * 32;
        float s = 0.f;
#pragma unroll
        for (int yq = 0; yq < 8; ++yq) {
            const float4 w = *reinterpret_cast<const float4*>(wb + yq * 4);
            s += brow[yq * 4 + 0] * w.x + brow[yq * 4 + 1] * w.y +
                 brow[yq * 4 + 2] * w.z + brow[yq * 4 + 3] * w.w;
        }
        accp[pp] = s;
    }
    *reinterpret_cast<float4*>(T + j * 2048 + xp0) = acc;
}

// out[i][j][p] = (sum_x a[i][x] * T[j][x*64+p] + b_out[p]) * op_norm   grid=576
// Block = 16i x 16j. Wave wv owns j = jt*16 + wv*4 + (lane>>4); p4=(lane&15)*4.
// a-tile staged in LDS, read as ds_read_b128 broadcast.
__global__ __launch_bounds__(256) void k_main3(const float* __restrict__ ab,
                                               const float* __restrict__ T,
                                               const float* __restrict__ b_out,
                                               const float* __restrict__ op_norm,
                                               float* __restrict__ out) {
    const int t    = threadIdx.x;
    const int lane = t & 63;
    const int wv   = __builtin_amdgcn_readfirstlane(t >> 6);
    const int jt   = blockIdx.x % 24;          // same-jt blocks share an XCD (24%8==0)
    const int it   = blockIdx.x / 24;
    const int jq   = lane >> 4;
    const int p4   = (lane & 15) * 4;
    const int j    = jt * 16 + wv * 4 + jq;
    const int i0   = it * 16;

    __shared__ float a_sh[16][32];             // 2 KB
    if (t < 128) {
        const int ii = t >> 3, xq8 = t & 7;
        *reinterpret_cast<float4*>(&a_sh[ii][xq8 * 4]) =
            *reinterpret_cast<const float4*>(ab + (i0 + ii) * 64 + xq8 * 4);
    }
    __syncthreads();

    const float4 bo  = *reinterpret_cast<const float4*>(b_out + p4);
    const float norm = op_norm[0];

    float4 acc[16];
#pragma unroll
    for (int i = 0; i < 16; ++i) acc[i] = bo;

    const float* Tj = T + j * 2048 + p4;

#pragma unroll 2
    for (int xq = 0; xq < 8; ++xq) {
        float4 t4[4];
#pragma unroll
        for (int s = 0; s < 4; ++s)
            t4[s] = *reinterpret_cast<const float4*>(Tj + (xq * 4 + s) * 64);
#pragma unroll
        for (int i = 0; i < 16; ++i) {
            const float4 av = *reinterpret_cast<const float4*>(&a_sh[i][xq * 4]); // LDS broadcast
            acc[i].x += av.x * t4[0].x + av.y * t4[1].x + av.z * t4[2].x + av.w * t4[3].x;
            acc[i].y += av.x * t4[0].y + av.y * t4[1].y + av.z * t4[2].y + av.w * t4[3].y;
            acc[i].z += av.x * t4[0].z + av.y * t4[1].z + av.z * t4[2].z + av.w * t4[3].z;
            acc[i].w += av.x * t4[0].w + av.y * t4[1].w + av.z * t4[2].w + av.w * t4[3].w;
        }
    }

#pragma unroll
    for (int i = 0; i < 16; ++i) {
        float4 r;
        r.x = acc[i].x * norm; r.y = acc[i].y * norm;
        r.z = acc[i].z * norm; r.w = acc[i].w * norm;
        *reinterpret_cast<float4*>(out + ((i0 + i) * NLOC + j) * 64 + p4) = r; // 1 KB/wave
    }
}

extern "C" void kernel_launch(void* const* d_in, const int* in_sizes, int n_in,
                              void* d_out, int out_size, void* d_ws, size_t ws_size,
                              hipStream_t stream) {
    const float* m       = (const float*)d_in[0];
    // d_in[1] = nlist (unused by the reference computation)
    const float* op_mask = (const float*)d_in[2];
    const float* op_norm = (const float*)d_in[3];
    const float* W_in    = (const float*)d_in[4];
    const float* b_in    = (const float*)d_in[5];
    const float* W_out   = (const float*)d_in[6];
    const float* b_out   = (const float*)d_in[7];
    float* out = (float*)d_out;

    float* ab = (float*)d_ws;                      // 384*64 f32
    float* T  = (float*)((char*)d_ws + 98304);     // 384*32*64 f32

    k_ab   <<<96,  256, 0, stream>>>(m, W_in, b_in, op_mask, ab);
    k_T    <<<768, 256, 0, stream>>>(ab, W_out, T);
    k_main3<<<576, 256, 0, stream>>>(ab, T, b_out, op_norm, out);
}